// Round 1
// baseline (431.816 us; speedup 1.0000x reference)
//
#include <hip/hip_runtime.h>

#define FFT_N 4096
#define RADIX 8
#define NT    512   // FFT_N / RADIX threads per block

// LDS pad: addr -> addr + addr/32 breaks the stride-8 scatter conflicts
__device__ __forceinline__ int padidx(int i) { return i + (i >> 5); }

// 8-point DFT, X[k] = sum_n x[n] e^{-2pi i n k / 8}, in/out natural order.
// DIF with bit-reversed positions relabeled on output. Hand-verified on
// impulse inputs (delta_0 -> all ones, delta_1 -> W8^k table).
__device__ __forceinline__ void dft8(float vr[8], float vi[8]) {
  const float C = 0.70710678118654752440f;
  // dist 4, twiddles W8^{0..3} = 1, (C,-C), -i, (-C,-C)
  float t0r = vr[0] + vr[4], t0i = vi[0] + vi[4];
  float t4r = vr[0] - vr[4], t4i = vi[0] - vi[4];
  float t1r = vr[1] + vr[5], t1i = vi[1] + vi[5];
  float d1r = vr[1] - vr[5], d1i = vi[1] - vi[5];
  float t5r = C * (d1r + d1i), t5i = C * (d1i - d1r);   // * (C - iC)
  float t2r = vr[2] + vr[6], t2i = vi[2] + vi[6];
  float d2r = vr[2] - vr[6], d2i = vi[2] - vi[6];
  float t6r = d2i, t6i = -d2r;                          // * (-i)
  float t3r = vr[3] + vr[7], t3i = vi[3] + vi[7];
  float d3r = vr[3] - vr[7], d3i = vi[3] - vi[7];
  float t7r = C * (d3i - d3r), t7i = -C * (d3r + d3i);  // * (-C - iC)
  // dist 2, twiddles 1, -i
  float u0r = t0r + t2r, u0i = t0i + t2i;
  float u2r = t0r - t2r, u2i = t0i - t2i;
  float u1r = t1r + t3r, u1i = t1i + t3i;
  float dar = t1r - t3r, dai = t1i - t3i;
  float u3r = dai, u3i = -dar;                          // * (-i)
  float u4r = t4r + t6r, u4i = t4i + t6i;
  float u6r = t4r - t6r, u6i = t4i - t6i;
  float u5r = t5r + t7r, u5i = t5i + t7i;
  float dbr = t5r - t7r, dbi = t5i - t7i;
  float u7r = dbi, u7i = -dbr;                          // * (-i)
  // dist 1; positions are bit-reversed -> write natural-order bins
  vr[0] = u0r + u1r; vi[0] = u0i + u1i;
  vr[4] = u0r - u1r; vi[4] = u0i - u1i;
  vr[2] = u2r + u3r; vi[2] = u2i + u3i;
  vr[6] = u2r - u3r; vi[6] = u2i - u3i;
  vr[1] = u4r + u5r; vi[1] = u4i + u5i;
  vr[5] = u4r - u5r; vi[5] = u4i - u5i;
  vr[3] = u6r + u7r; vi[3] = u6i + u7i;
  vr[7] = u6r - u7r; vi[7] = u6i - u7i;
}

// v[r] *= exp(-2pi i * r * jm / (Ns*RADIX));  invD = 1/(Ns*RADIX)
__device__ __forceinline__ void twiddle(float vr[8], float vi[8], int jm, float invD) {
  float ang = -6.28318530717958647692f * (float)jm * invD;  // |ang| < 0.79
  float c1, s1;
  __sincosf(ang, &s1, &c1);
  float cr = c1, sr = s1;
#pragma unroll
  for (int r = 1; r < 8; ++r) {
    float tr = vr[r] * cr - vi[r] * sr;
    float ti = vr[r] * sr + vi[r] * cr;
    vr[r] = tr; vi[r] = ti;
    float nc = cr * c1 - sr * s1;   // advance w^r -> w^(r+1)
    float ns = cr * s1 + sr * c1;
    cr = nc; sr = ns;
  }
}

// Radix-8 Stockham autosort, 4 stages (Ns = 1, 8, 64, 512), one block per row.
// Stage s: v[r] = src[j + r*NT]; v[r] *= W^(r*(j%Ns)); dft8;
//          dst[(j/Ns)*Ns*8 + (j%Ns) + r*Ns] = v[r]
// In-place single LDS buffer: read-all / barrier / write-all / barrier.
__global__ __launch_bounds__(NT) void fft4096_kernel(
    const float* __restrict__ xre, const float* __restrict__ xim,
    float* __restrict__ yre, float* __restrict__ yim) {
  __shared__ float sre[FFT_N + (FFT_N >> 5)];
  __shared__ float sim[FFT_N + (FFT_N >> 5)];
  const int row = blockIdx.x;
  const int j = threadIdx.x;
  const float* __restrict__ xr = xre + (size_t)row * FFT_N;
  const float* __restrict__ xi = xim + (size_t)row * FFT_N;

  float vr[8], vi[8];

  // ---- stage 0: Ns = 1, global -> LDS, twiddle = 1 ----
#pragma unroll
  for (int r = 0; r < 8; ++r) { vr[r] = xr[j + r * NT]; vi[r] = xi[j + r * NT]; }
  dft8(vr, vi);
#pragma unroll
  for (int r = 0; r < 8; ++r) {
    int d = padidx(j * 8 + r);
    sre[d] = vr[r]; sim[d] = vi[r];
  }
  __syncthreads();

  // ---- stage 1: Ns = 8 ----
#pragma unroll
  for (int r = 0; r < 8; ++r) {
    int s = padidx(j + r * NT);
    vr[r] = sre[s]; vi[r] = sim[s];
  }
  __syncthreads();
  twiddle(vr, vi, j & 7, 1.0f / 64.0f);
  dft8(vr, vi);
  {
    int base = (j >> 3) * 64 + (j & 7);
#pragma unroll
    for (int r = 0; r < 8; ++r) {
      int d = padidx(base + r * 8);
      sre[d] = vr[r]; sim[d] = vi[r];
    }
  }
  __syncthreads();

  // ---- stage 2: Ns = 64 ----
#pragma unroll
  for (int r = 0; r < 8; ++r) {
    int s = padidx(j + r * NT);
    vr[r] = sre[s]; vi[r] = sim[s];
  }
  __syncthreads();
  twiddle(vr, vi, j & 63, 1.0f / 512.0f);
  dft8(vr, vi);
  {
    int base = (j >> 6) * 512 + (j & 63);
#pragma unroll
    for (int r = 0; r < 8; ++r) {
      int d = padidx(base + r * 64);
      sre[d] = vr[r]; sim[d] = vi[r];
    }
  }
  __syncthreads();

  // ---- stage 3: Ns = 512, LDS -> global ----
#pragma unroll
  for (int r = 0; r < 8; ++r) {
    int s = padidx(j + r * NT);
    vr[r] = sre[s]; vi[r] = sim[s];
  }
  twiddle(vr, vi, j, 1.0f / 4096.0f);
  dft8(vr, vi);
  float* __restrict__ your = yre + (size_t)row * FFT_N;
  float* __restrict__ youi = yim + (size_t)row * FFT_N;
#pragma unroll
  for (int r = 0; r < 8; ++r) {
    your[j + r * NT] = vr[r];
    youi[j + r * NT] = vi[r];
  }
}

extern "C" void kernel_launch(void* const* d_in, const int* in_sizes, int n_in,
                              void* d_out, int out_size, void* d_ws, size_t ws_size,
                              hipStream_t stream) {
  const float* xre = (const float*)d_in[0];
  const float* xim = (const float*)d_in[1];
  float* out = (float*)d_out;
  const int total = in_sizes[0];        // B * N
  const int B = total / FFT_N;
  float* yre = out;
  float* yim = out + (size_t)total;
  fft4096_kernel<<<dim3(B), dim3(NT), 0, stream>>>(xre, xim, yre, yim);
}

// Round 2
// 431.071 us; speedup vs baseline: 1.0017x; 1.0017x over previous
//
#include <hip/hip_runtime.h>

#define FFT_N 4096
#define RADIX 8
#define NT    512   // FFT_N / RADIX threads per block

// LDS pad: addr -> addr + addr/32 breaks the stride-8 scatter conflicts
__device__ __forceinline__ int padidx(int i) { return i + (i >> 5); }

// 8-point DFT, X[k] = sum_n x[n] e^{-2pi i n k / 8}, in/out natural order.
__device__ __forceinline__ void dft8(float vr[8], float vi[8]) {
  const float C = 0.70710678118654752440f;
  float t0r = vr[0] + vr[4], t0i = vi[0] + vi[4];
  float t4r = vr[0] - vr[4], t4i = vi[0] - vi[4];
  float t1r = vr[1] + vr[5], t1i = vi[1] + vi[5];
  float d1r = vr[1] - vr[5], d1i = vi[1] - vi[5];
  float t5r = C * (d1r + d1i), t5i = C * (d1i - d1r);   // * (C - iC)
  float t2r = vr[2] + vr[6], t2i = vi[2] + vi[6];
  float d2r = vr[2] - vr[6], d2i = vi[2] - vi[6];
  float t6r = d2i, t6i = -d2r;                          // * (-i)
  float t3r = vr[3] + vr[7], t3i = vi[3] + vi[7];
  float d3r = vr[3] - vr[7], d3i = vi[3] - vi[7];
  float t7r = C * (d3i - d3r), t7i = -C * (d3r + d3i);  // * (-C - iC)
  float u0r = t0r + t2r, u0i = t0i + t2i;
  float u2r = t0r - t2r, u2i = t0i - t2i;
  float u1r = t1r + t3r, u1i = t1i + t3i;
  float dar = t1r - t3r, dai = t1i - t3i;
  float u3r = dai, u3i = -dar;                          // * (-i)
  float u4r = t4r + t6r, u4i = t4i + t6i;
  float u6r = t4r - t6r, u6i = t4i - t6i;
  float u5r = t5r + t7r, u5i = t5i + t7i;
  float dbr = t5r - t7r, dbi = t5i - t7i;
  float u7r = dbi, u7i = -dbr;                          // * (-i)
  vr[0] = u0r + u1r; vi[0] = u0i + u1i;
  vr[4] = u0r - u1r; vi[4] = u0i - u1i;
  vr[2] = u2r + u3r; vi[2] = u2i + u3i;
  vr[6] = u2r - u3r; vi[6] = u2i - u3i;
  vr[1] = u4r + u5r; vi[1] = u4i + u5i;
  vr[5] = u4r - u5r; vi[5] = u4i - u5i;
  vr[3] = u6r + u7r; vi[3] = u6i + u7i;
  vr[7] = u6r - u7r; vi[7] = u6i - u7i;
}

// v[r] *= exp(-2pi i * r * jm / (Ns*RADIX));  invD = 1/(Ns*RADIX)
// NATIVE __sinf/__cosf (v_sin_f32/v_cos_f32) — NOT __sincosf, which expands
// to the accurate OCML path (huge instr count + register pressure).
__device__ __forceinline__ void twiddle(float vr[8], float vi[8], int jm, float invD) {
  float ang = -6.28318530717958647692f * (float)jm * invD;  // |ang| < 0.79
  float c1 = __cosf(ang);
  float s1 = __sinf(ang);
  float cr = c1, sr = s1;
#pragma unroll
  for (int r = 1; r < 8; ++r) {
    float tr = vr[r] * cr - vi[r] * sr;
    float ti = vr[r] * sr + vi[r] * cr;
    vr[r] = tr; vi[r] = ti;
    float nc = cr * c1 - sr * s1;   // advance w^r -> w^(r+1)
    float ns = cr * s1 + sr * c1;
    cr = nc; sr = ns;
  }
}

// Radix-8 Stockham autosort, 4 stages (Ns = 1, 8, 64, 512), one block per row.
__global__ __launch_bounds__(NT, 4) void fft4096_kernel(
    const float* __restrict__ xre, const float* __restrict__ xim,
    float* __restrict__ yre, float* __restrict__ yim) {
  __shared__ float sre[FFT_N + (FFT_N >> 5)];
  __shared__ float sim[FFT_N + (FFT_N >> 5)];
  const int row = blockIdx.x;
  const int j = threadIdx.x;
  const float* __restrict__ xr = xre + (size_t)row * FFT_N;
  const float* __restrict__ xi = xim + (size_t)row * FFT_N;

  float vr[8], vi[8];

  // ---- stage 0: Ns = 1, global -> LDS, twiddle = 1 ----
#pragma unroll
  for (int r = 0; r < 8; ++r) { vr[r] = xr[j + r * NT]; vi[r] = xi[j + r * NT]; }
  dft8(vr, vi);
#pragma unroll
  for (int r = 0; r < 8; ++r) {
    int d = padidx(j * 8 + r);
    sre[d] = vr[r]; sim[d] = vi[r];
  }
  __syncthreads();

  // ---- stage 1: Ns = 8 ----
#pragma unroll
  for (int r = 0; r < 8; ++r) {
    int s = padidx(j + r * NT);
    vr[r] = sre[s]; vi[r] = sim[s];
  }
  __syncthreads();
  twiddle(vr, vi, j & 7, 1.0f / 64.0f);
  dft8(vr, vi);
  {
    int base = (j >> 3) * 64 + (j & 7);
#pragma unroll
    for (int r = 0; r < 8; ++r) {
      int d = padidx(base + r * 8);
      sre[d] = vr[r]; sim[d] = vi[r];
    }
  }
  __syncthreads();

  // ---- stage 2: Ns = 64 ----
#pragma unroll
  for (int r = 0; r < 8; ++r) {
    int s = padidx(j + r * NT);
    vr[r] = sre[s]; vi[r] = sim[s];
  }
  __syncthreads();
  twiddle(vr, vi, j & 63, 1.0f / 512.0f);
  dft8(vr, vi);
  {
    int base = (j >> 6) * 512 + (j & 63);
#pragma unroll
    for (int r = 0; r < 8; ++r) {
      int d = padidx(base + r * 64);
      sre[d] = vr[r]; sim[d] = vi[r];
    }
  }
  __syncthreads();

  // ---- stage 3: Ns = 512, LDS -> global ----
#pragma unroll
  for (int r = 0; r < 8; ++r) {
    int s = padidx(j + r * NT);
    vr[r] = sre[s]; vi[r] = sim[s];
  }
  twiddle(vr, vi, j, 1.0f / 4096.0f);
  dft8(vr, vi);
  float* __restrict__ your = yre + (size_t)row * FFT_N;
  float* __restrict__ youi = yim + (size_t)row * FFT_N;
#pragma unroll
  for (int r = 0; r < 8; ++r) {
    your[j + r * NT] = vr[r];
    youi[j + r * NT] = vi[r];
  }
}

extern "C" void kernel_launch(void* const* d_in, const int* in_sizes, int n_in,
                              void* d_out, int out_size, void* d_ws, size_t ws_size,
                              hipStream_t stream) {
  const float* xre = (const float*)d_in[0];
  const float* xim = (const float*)d_in[1];
  float* out = (float*)d_out;
  const int total = in_sizes[0];        // B * N
  const int B = total / FFT_N;
  float* yre = out;
  float* yim = out + (size_t)total;
  fft4096_kernel<<<dim3(B), dim3(NT), 0, stream>>>(xre, xim, yre, yim);
}